// Round 2
// baseline (684.364 us; speedup 1.0000x reference)
//
#include <hip/hip_runtime.h>
#include <math.h>

#define N_IMG 4096
#define NBC   512         // cols per block (256 threads x 2 cols)
#define H_OUT 32          // harris output rows per block
#define HR    38          // H_OUT + 6 halo
#define NMS_HOUT 16
#define NMS_HR   22

struct W7 { float w[7]; };

__device__ __forceinline__ unsigned f2k(float f) {
    unsigned u = __float_as_uint(f);
    return (u & 0x80000000u) ? ~u : (u | 0x80000000u);
}
__device__ __forceinline__ float k2f(unsigned k) {
    unsigned u = (k & 0x80000000u) ? (k & 0x7fffffffu) : ~k;
    return __uint_as_float(u);
}

// Dual-rank radix-select step, runnable by any single 256-thread block.
// Reads ghist with agent-scope atomic loads (cross-XCD safe after acquire fence).
__device__ __forceinline__ void select_body(unsigned* __restrict__ ghist,
                                            unsigned* __restrict__ state,
                                            int shift, int bins, int last,
                                            int tid)
{
    __shared__ unsigned scan[256];
    __shared__ unsigned res_b[2], res_r[2];
    const int per = bins >> 8;                 // 16 or 1 (constant after inlining)
    unsigned p1 = state[0], p2 = state[1];
    unsigned r1 = state[2], r2 = state[3];
    const bool dual = (p1 != p2);

    for (int q = 0; q < 2; q++) {
        unsigned* h = (q == 1 && dual) ? (ghist + 4096) : ghist;
        const unsigned rank = (q == 0) ? r1 : r2;
        const int base = tid * per;
        unsigned loc[16];
        unsigned s = 0;
        #pragma unroll
        for (int i = 0; i < 16; i++) {
            unsigned c = 0u;
            if (i < per)
                c = __hip_atomic_load(&h[base + i], __ATOMIC_RELAXED, __HIP_MEMORY_SCOPE_AGENT);
            loc[i] = c; s += c;
        }
        scan[tid] = s;
        __syncthreads();
        unsigned v = s;
        #pragma unroll
        for (int off = 1; off < 256; off <<= 1) {
            unsigned t = (tid >= off) ? scan[tid - off] : 0u;
            __syncthreads();
            v += t;
            scan[tid] = v;
            __syncthreads();
        }
        const unsigned excl = v - s;
        if (rank >= excl && rank < v) {
            unsigned rr = rank - excl;
            unsigned b = 0xFFFFFFFFu;
            #pragma unroll
            for (int i = 0; i < 16; i++) {
                if (i < per && b == 0xFFFFFFFFu) {
                    unsigned c = loc[i];
                    if (rr < c) b = (unsigned)(base + i);
                    else rr -= c;
                }
            }
            if (b == 0xFFFFFFFFu) { b = (unsigned)(base + per - 1); rr = 0; }
            res_b[q] = b; res_r[q] = rr;
        }
        __syncthreads();
    }
    if (tid == 0) {
        p1 |= res_b[0] << shift;  r1 = res_r[0];
        p2 |= res_b[1] << shift;  r2 = res_r[1];
        state[0] = p1; state[1] = p2; state[2] = r1; state[3] = r2;
        if (last) {
            float a = k2f(p1), b = k2f(p2);
            ((float*)state)[4] = 0.5f * (a + b);
        }
    }
    __syncthreads();
    for (int i = tid; i < 8192; i += 256) ghist[i] = 0;
}

// Last-block gate: returns true (block-uniform) for exactly one block after all
// blocks' prior device writes are visible.
__device__ __forceinline__ bool last_block_gate(unsigned* cnt, int tid, unsigned nblocks)
{
    __shared__ unsigned lastFlag;
    __threadfence();                 // release: this thread's ghist atomics visible
    __syncthreads();                 // all threads of block fenced
    if (tid == 0) {
        unsigned v = atomicAdd(cnt, 1u);
        lastFlag = (v == nblocks - 1u) ? 1u : 0u;
    }
    __syncthreads();
    if (lastFlag) {
        __threadfence();             // acquire
        return true;
    }
    return false;
}

// Register-rolling strip kernel: sobel + products + separable 7x7 gaussian +
// Harris R + fused level-0 histogram + fused (last-block) level-0 select.
// v3: 2 cols/thread to halve register state (ring 42 + rows 30) -> 4 waves/SIMD.
__global__ __launch_bounds__(256, 4) void harris_kernel(const float* __restrict__ x,
                                                        float* __restrict__ R,
                                                        unsigned* __restrict__ ghist,
                                                        unsigned* __restrict__ state,
                                                        unsigned* __restrict__ cnt,
                                                        W7 wp)
{
    __shared__ unsigned histo[4096];
    const int tid = threadIdx.x;
    for (int i = tid; i < 4096; i += 256) histo[i] = 0;
    __syncthreads();

    const int row0 = blockIdx.y * H_OUT;
    const int jc   = blockIdx.x * NBC + tid * 2;   // first owned column
    const float* w = wp.w;
    const bool edge = (jc < 4) || (jc + 5 >= N_IMG);   // 2 lanes per grid edge

    float xm[10], xc[10], xp[10];                  // rolling x rows, cols jc-4..jc+5
    float hxx[7][2], hyy[7][2], hxy[7][2];         // 7-deep ring of h rows

    auto loadrow = [&](int ri, float* d) {
        if ((unsigned)ri < N_IMG) {
            const float* p = x + (size_t)ri * N_IMG;
            float2 v0 = make_float2(0.f, 0.f), v1 = make_float2(0.f, 0.f);
            float2 v3 = make_float2(0.f, 0.f), v4 = make_float2(0.f, 0.f);
            if (jc >= 4)            v0 = *(const float2*)(p + jc - 4);
            if (jc >= 2)            v1 = *(const float2*)(p + jc - 2);
            float2 v2 = *(const float2*)(p + jc);
            if (jc + 3 < N_IMG)     v3 = *(const float2*)(p + jc + 2);
            if (jc + 5 < N_IMG)     v4 = *(const float2*)(p + jc + 4);
            d[0]=v0.x; d[1]=v0.y; d[2]=v1.x; d[3]=v1.y; d[4]=v2.x; d[5]=v2.y;
            d[6]=v3.x; d[7]=v3.y; d[8]=v4.x; d[9]=v4.y;
        } else {
            #pragma unroll
            for (int t = 0; t < 10; t++) d[t] = 0.f;
        }
    };

    loadrow(row0 - 4, xm);
    loadrow(row0 - 3, xc);

    int curb = -1; unsigned rcnt = 0;   // histogram run-length state

    for (int it = 0; it < 6; ++it) {
        #pragma unroll
        for (int k = 0; k < 7; ++k) {
            const int r = it * 7 + k;          // ring slot == k (r mod 7)
            if (r < HR) {
                const int ri = row0 + r - 3;   // image row of this h row
                loadrow(ri + 1, xp);

                float sxx[2] = {0,0}, syy[2] = {0,0}, sxy[2] = {0,0};
                if ((unsigned)ri < N_IMG) {
                    float dc[10], rd[10];
                    #pragma unroll
                    for (int t = 0; t < 10; t++) {
                        dc[t] = fmaf(2.f, xc[t], xm[t]) + xp[t];
                        rd[t] = xp[t] - xm[t];
                    }
                    float ixv[8], iyv[8];
                    #pragma unroll
                    for (int t = 0; t < 8; t++) {
                        ixv[t] = dc[t+2] - dc[t];
                        iyv[t] = fmaf(2.f, rd[t+1], rd[t]) + rd[t+2];
                    }
                    if (edge) {                // execz-skipped for interior waves
                        #pragma unroll
                        for (int t = 0; t < 8; t++)
                            if ((unsigned)(jc - 3 + t) >= N_IMG) { ixv[t] = 0.f; iyv[t] = 0.f; }
                    }
                    #pragma unroll
                    for (int t = 0; t < 8; t++) {
                        float ix = ixv[t], iy = iyv[t];
                        float xx = ix*ix, yy = iy*iy, xy = ix*iy;
                        #pragma unroll
                        for (int o = 0; o < 2; o++) {
                            const int v = t - o;
                            if (v >= 0 && v < 7) {
                                sxx[o] = fmaf(w[v], xx, sxx[o]);
                                syy[o] = fmaf(w[v], yy, syy[o]);
                                sxy[o] = fmaf(w[v], xy, sxy[o]);
                            }
                        }
                    }
                }
                #pragma unroll
                for (int o = 0; o < 2; o++) {
                    hxx[k][o] = sxx[o]; hyy[k][o] = syy[o]; hxy[k][o] = sxy[o];
                }

                if (r >= 6) {
                    float hp[2];
                    #pragma unroll
                    for (int o = 0; o < 2; o++) {
                        float ax = 0.f, ay = 0.f, az = 0.f;
                        #pragma unroll
                        for (int u = 0; u < 7; u++) {
                            const int s = (k + 1 + u) % 7;   // static
                            ax = fmaf(w[u], hxx[s][o], ax);
                            ay = fmaf(w[u], hyy[s][o], ay);
                            az = fmaf(w[u], hxy[s][o], az);
                        }
                        float tr = ax + ay;
                        hp[o] = ax*ay - az*az - 0.05f*tr*tr;
                    }
                    const int orow = row0 + r - 6;
                    float2 stv; stv.x = hp[0]; stv.y = hp[1];
                    *(float2*)(R + (size_t)orow * N_IMG + jc) = stv;
                    #pragma unroll
                    for (int o = 0; o < 2; o++) {
                        int b = (int)(f2k(hp[o]) >> 20);
                        if (b == curb) rcnt++;
                        else { if (curb >= 0) atomicAdd(&histo[curb], rcnt); curb = b; rcnt = 1; }
                    }
                }
                #pragma unroll
                for (int t = 0; t < 10; t++) { xm[t] = xc[t]; xc[t] = xp[t]; }
            }
        }
    }
    if (curb >= 0) atomicAdd(&histo[curb], rcnt);
    __syncthreads();
    for (int i = tid; i < 4096; i += 256) {
        unsigned c = histo[i];
        if (c) atomicAdd(&ghist[i], c);
    }

    // fused level-0 select (last block only)
    if (last_block_gate(cnt, tid, gridDim.x * gridDim.y))
        select_body(ghist, state, 20, 4096, 0, tid);
}

// dual-rank radix-select histogram pass + fused (last-block) select
__global__ __launch_bounds__(256) void hist_kernel(const float* __restrict__ R,
                                                   unsigned* __restrict__ ghist,
                                                   unsigned* __restrict__ state,
                                                   unsigned* __restrict__ cnt,
                                                   unsigned mask, int shift, int bins,
                                                   int last)
{
    __shared__ unsigned h[2][4096];
    const int tid = threadIdx.x;
    for (int i = tid; i < 8192; i += 256) ((unsigned*)h)[i] = 0;
    __syncthreads();
    const unsigned p1 = state[0], p2 = state[1];
    const bool dual = (p1 != p2);
    const int n4 = (N_IMG * N_IMG) / 4;
    int curb1 = -1; unsigned cnt1 = 0;
    int curb2 = -1; unsigned cnt2 = 0;
    const float4* R4 = (const float4*)R;
    for (int i = blockIdx.x * 256 + tid; i < n4; i += gridDim.x * 256) {
        float4 v = R4[i];
        float vv[4] = {v.x, v.y, v.z, v.w};
        #pragma unroll
        for (int t = 0; t < 4; t++) {
            unsigned k = f2k(vv[t]);
            if ((k & mask) == p1) {
                int b = (int)((k >> shift) & (unsigned)(bins - 1));
                if (b == curb1) cnt1++;
                else { if (cnt1) atomicAdd(&h[0][curb1], cnt1); curb1 = b; cnt1 = 1; }
            }
            if (dual && (k & mask) == p2) {
                int b = (int)((k >> shift) & (unsigned)(bins - 1));
                if (b == curb2) cnt2++;
                else { if (cnt2) atomicAdd(&h[1][curb2], cnt2); curb2 = b; cnt2 = 1; }
            }
        }
    }
    if (cnt1) atomicAdd(&h[0][curb1], cnt1);
    if (cnt2) atomicAdd(&h[1][curb2], cnt2);
    __syncthreads();
    for (int i = tid; i < bins; i += 256) {
        unsigned c0 = h[0][i]; if (c0) atomicAdd(&ghist[i], c0);
        if (dual) { unsigned c1 = h[1][i]; if (c1) atomicAdd(&ghist[4096 + i], c1); }
    }

    if (last_block_gate(cnt, tid, gridDim.x))
        select_body(ghist, state, shift, bins, last, tid);
}

__global__ __launch_bounds__(256) void init_kernel(unsigned* __restrict__ ghist,
                                                   unsigned* __restrict__ state,
                                                   unsigned* __restrict__ cnt)
{
    const int tid = threadIdx.x;
    for (int i = tid; i < 8192; i += 256) ghist[i] = 0;
    if (tid == 0) {
        state[0] = 0u; state[1] = 0u;
        state[2] = 8388607u;   // N/2 - 1
        state[3] = 8388608u;   // N/2
        state[4] = 0u;
        cnt[0] = 0u; cnt[1] = 0u; cnt[2] = 0u;
    }
}

// Register-rolling NMS: threshold + separable 7x7 max + compare.
// v3: 2 cols/thread, no cross-row input carry -> ~35 live regs -> 8 waves/SIMD;
//     H_OUT=16 -> 2048 blocks = 8 blocks/CU.
__global__ __launch_bounds__(256, 8) void nms_kernel(const float* __restrict__ R,
                                                     const unsigned* __restrict__ state,
                                                     float* __restrict__ out)
{
    const int tid  = threadIdx.x;
    const int row0 = blockIdx.y * NMS_HOUT;
    const int jc   = blockIdx.x * NBC + tid * 2;
    const float med = ((const float*)state)[4];

    float hm[7][2], ct[7][2];

    for (int it = 0; it < 4; ++it) {
        #pragma unroll
        for (int k = 0; k < 7; ++k) {
            const int r = it * 7 + k;
            if (r < NMS_HR) {
                const int ri = row0 + r - 3;
                float a[10];
                if ((unsigned)ri < N_IMG) {
                    const float* p = R + (size_t)ri * N_IMG;
                    float2 v2 = *(const float2*)(p + jc);
                    a[4] = (v2.x >= med) ? v2.x : 0.f;
                    a[5] = (v2.y >= med) ? v2.y : 0.f;
                    if (jc >= 4) {
                        float2 v0 = *(const float2*)(p + jc - 4);
                        a[0] = (v0.x >= med) ? v0.x : 0.f;
                        a[1] = (v0.y >= med) ? v0.y : 0.f;
                    } else { a[0] = a[1] = -INFINITY; }
                    if (jc >= 2) {
                        float2 v1 = *(const float2*)(p + jc - 2);
                        a[2] = (v1.x >= med) ? v1.x : 0.f;
                        a[3] = (v1.y >= med) ? v1.y : 0.f;
                    } else { a[2] = a[3] = -INFINITY; }
                    if (jc + 3 < N_IMG) {
                        float2 v3 = *(const float2*)(p + jc + 2);
                        a[6] = (v3.x >= med) ? v3.x : 0.f;
                        a[7] = (v3.y >= med) ? v3.y : 0.f;
                    } else { a[6] = a[7] = -INFINITY; }
                    if (jc + 5 < N_IMG) {
                        float2 v4 = *(const float2*)(p + jc + 4);
                        a[8] = (v4.x >= med) ? v4.x : 0.f;
                        a[9] = (v4.y >= med) ? v4.y : 0.f;
                    } else { a[8] = a[9] = -INFINITY; }
                } else {
                    #pragma unroll
                    for (int t = 0; t < 10; t++) a[t] = -INFINITY;
                }
                #pragma unroll
                for (int o = 0; o < 2; o++) {
                    float m = a[o+1];
                    #pragma unroll
                    for (int t = 2; t <= 7; t++) m = fmaxf(m, a[o+t]);
                    hm[k][o] = m;
                    ct[k][o] = a[4+o];
                }
                if (r >= 6) {
                    float op[2];
                    #pragma unroll
                    for (int o = 0; o < 2; o++) {
                        float m = hm[(k+1) % 7][o];
                        #pragma unroll
                        for (int u = 1; u < 7; u++) m = fmaxf(m, hm[(k+1+u) % 7][o]);
                        float c = ct[(k+4) % 7][o];
                        op[o] = (c != m) ? 0.f : m;
                    }
                    const int orow = row0 + r - 6;
                    float2 ov; ov.x = op[0]; ov.y = op[1];
                    *(float2*)(out + (size_t)orow * N_IMG + jc) = ov;
                }
            }
        }
    }
}

extern "C" void kernel_launch(void* const* d_in, const int* in_sizes, int n_in,
                              void* d_out, int out_size, void* d_ws, size_t ws_size,
                              hipStream_t stream)
{
    const float* x = (const float*)d_in[0];
    float* R = (float*)d_ws;                                   // 64 MB
    unsigned* ghist = (unsigned*)((char*)d_ws + (size_t)N_IMG * N_IMG * 4);
    unsigned* state = ghist + 8192;
    unsigned* cntb  = state + 16;
    float* out = (float*)d_out;

    W7 wp;
    {
        double g[7], s = 0.0;
        for (int i = 0; i < 7; i++) { double ax = (double)i - 3.0; g[i] = exp(-(ax*ax)/50.0); s += g[i]; }
        for (int i = 0; i < 7; i++) wp.w[i] = (float)(g[i] / s);
    }

    dim3 hgrid(N_IMG / NBC, N_IMG / H_OUT);       // (8, 128) = 1024 blocks
    dim3 ngrid(N_IMG / NBC, N_IMG / NMS_HOUT);    // (8, 256) = 2048 blocks

    init_kernel<<<1, 256, 0, stream>>>(ghist, state, cntb);
    harris_kernel<<<hgrid, 256, 0, stream>>>(x, R, ghist, state, cntb + 0, wp);  // + level-0 hist + select
    hist_kernel<<<2048, 256, 0, stream>>>(R, ghist, state, cntb + 1, 0xFFF00000u, 8, 4096, 0);
    hist_kernel<<<2048, 256, 0, stream>>>(R, ghist, state, cntb + 2, 0xFFFFFF00u, 0, 256, 1);
    nms_kernel<<<ngrid, 256, 0, stream>>>(R, state, out);
}

// Round 3
// 299.128 us; speedup vs baseline: 2.2879x; 2.2879x over previous
//
#include <hip/hip_runtime.h>
#include <math.h>

#define N_IMG 4096
#define NBC   1024        // cols per block (256 threads x 4 cols)
#define H_OUT 32          // output rows per block
#define HR    38          // processed rows per block (H_OUT + 6 halo)
#define NPIX  (N_IMG * N_IMG)

struct W7 { float w[7]; };

__device__ __forceinline__ unsigned f2k(float f) {
    unsigned u = __float_as_uint(f);
    return (u & 0x80000000u) ? ~u : (u | 0x80000000u);
}
__device__ __forceinline__ float k2f(unsigned k) {
    unsigned u = (k & 0x80000000u) ? (k & 0x7fffffffu) : ~k;
    return __uint_as_float(u);
}

// ---------- per-block radix-select re-derivation (no fences, no gates) ----------
// Every block of a consumer kernel recomputes the select result from the
// PREVIOUS kernel's completed histogram (visible at kernel boundary).
struct SelState { unsigned p1, p2, r1, r2; };

template<int BINS>
__device__ void locate_pair(const unsigned* __restrict__ h0,
                            const unsigned* __restrict__ h1,
                            int shift, SelState& s)
{
    __shared__ unsigned scan[256];
    __shared__ unsigned resb[2], resr[2];
    const int tid = threadIdx.x;
    const int per = BINS / 256;
    const bool same = (h0 == h1);

    for (int q = 0; q < 2; q++) {
        if (q == 1 && same) break;
        const unsigned* __restrict__ h = q ? h1 : h0;
        const int base = tid * per;
        unsigned sum = 0;
        #pragma unroll
        for (int i = 0; i < per; i++) sum += h[base + i];
        __syncthreads();                  // protect scan[] reuse across calls
        scan[tid] = sum;
        __syncthreads();
        unsigned v = sum;
        #pragma unroll
        for (int off = 1; off < 256; off <<= 1) {
            unsigned t = (tid >= off) ? scan[tid - off] : 0u;
            __syncthreads();
            v += t;
            scan[tid] = v;
            __syncthreads();
        }
        const unsigned excl = v - sum;
        #pragma unroll
        for (int w = 0; w < 2; w++) {
            const unsigned rank = w ? s.r2 : s.r1;
            const bool mine = w ? (same || q == 1) : (q == 0);
            if (mine && rank >= excl && rank < v) {
                unsigned rr = rank - excl;
                for (int i = 0; i < per; i++) {
                    unsigned c = h[base + i];
                    if (rr < c) { resb[w] = (unsigned)(base + i); resr[w] = rr; break; }
                    rr -= c;
                }
            }
        }
        __syncthreads();
    }
    s.p1 |= resb[0] << shift; s.r1 = resr[0];
    s.p2 |= resb[1] << shift; s.r2 = resr[1];
}

__device__ __forceinline__ SelState derive0(const unsigned* __restrict__ g0) {
    SelState s; s.p1 = 0u; s.p2 = 0u;
    s.r1 = (unsigned)(NPIX / 2 - 1); s.r2 = (unsigned)(NPIX / 2);
    locate_pair<4096>(g0, g0, 20, s);
    return s;
}
__device__ __forceinline__ void derive1(const unsigned* __restrict__ g1, SelState& s) {
    const unsigned* h1 = (s.p1 != s.p2) ? (g1 + 4096) : g1;
    locate_pair<4096>(g1, h1, 8, s);
}
__device__ __forceinline__ void derive2(const unsigned* __restrict__ g2, SelState& s) {
    const unsigned* h1 = (s.p1 != s.p2) ? (g2 + 256) : g2;
    locate_pair<256>(g2, h1, 0, s);
}

// ---------- harris: sobel + products + separable 7x7 gaussian + R + level-0 hist ----------
// Round-0 body (best measured: 80 us). Register-rolling strip, no stencil LDS.
__global__ __launch_bounds__(256) void harris_kernel(const float* __restrict__ x,
                                                     float* __restrict__ R,
                                                     unsigned* __restrict__ g0,
                                                     W7 wp)
{
    __shared__ unsigned histo[4096];
    const int tid = threadIdx.x;
    for (int i = tid; i < 4096; i += 256) histo[i] = 0;
    __syncthreads();

    const int row0 = blockIdx.y * H_OUT;
    const int jc   = blockIdx.x * NBC + tid * 4;   // first owned column
    const float* w = wp.w;

    float xm[12], xc[12], xp[12];                  // rolling x rows (cols jc-4..jc+7)
    float hxx[7][4], hyy[7][4], hxy[7][4];         // 7-deep ring of h rows

    auto loadrow = [&](int ri, float* d) {
        if ((unsigned)ri < N_IMG) {
            const float* p = x + (size_t)ri * N_IMG;
            float4 v0 = make_float4(0.f,0.f,0.f,0.f), v2 = make_float4(0.f,0.f,0.f,0.f);
            if (jc >= 4) v0 = *(const float4*)(p + jc - 4);
            float4 v1 = *(const float4*)(p + jc);
            if (jc + 4 < N_IMG) v2 = *(const float4*)(p + jc + 4);
            d[0]=v0.x; d[1]=v0.y; d[2]=v0.z; d[3]=v0.w;
            d[4]=v1.x; d[5]=v1.y; d[6]=v1.z; d[7]=v1.w;
            d[8]=v2.x; d[9]=v2.y; d[10]=v2.z; d[11]=v2.w;
        } else {
            #pragma unroll
            for (int t = 0; t < 12; t++) d[t] = 0.f;
        }
    };

    loadrow(row0 - 4, xm);
    loadrow(row0 - 3, xc);

    int curb = -1; unsigned cnt = 0;   // histogram run-length state

    for (int it = 0; it < 6; ++it) {
        #pragma unroll
        for (int k = 0; k < 7; ++k) {
            const int r = it * 7 + k;          // ring slot == k (r mod 7)
            if (r < HR) {
                const int ri = row0 + r - 3;   // image row of this h row
                loadrow(ri + 1, xp);

                float sxx[4] = {0,0,0,0}, syy[4] = {0,0,0,0}, sxy[4] = {0,0,0,0};
                if ((unsigned)ri < N_IMG) {
                    float dc[12], rd[12];
                    #pragma unroll
                    for (int t = 0; t < 12; t++) {
                        dc[t] = xm[t] + 2.f * xc[t] + xp[t];
                        rd[t] = xp[t] - xm[t];
                    }
                    #pragma unroll
                    for (int t = 0; t < 10; t++) {
                        float ix = dc[t+2] - dc[t];
                        float iy = rd[t] + 2.f * rd[t+1] + rd[t+2];
                        if ((unsigned)(jc - 3 + t) >= N_IMG) { ix = 0.f; iy = 0.f; }
                        float xx = ix*ix, yy = iy*iy, xy = ix*iy;
                        #pragma unroll
                        for (int o = 0; o < 4; o++) {
                            int v = t - o;
                            if (v >= 0 && v < 7) {
                                sxx[o] = fmaf(w[v], xx, sxx[o]);
                                syy[o] = fmaf(w[v], yy, syy[o]);
                                sxy[o] = fmaf(w[v], xy, sxy[o]);
                            }
                        }
                    }
                }
                #pragma unroll
                for (int o = 0; o < 4; o++) {
                    hxx[k][o] = sxx[o]; hyy[k][o] = syy[o]; hxy[k][o] = sxy[o];
                }

                if (r >= 6) {
                    float4 h;
                    float* hp = &h.x;
                    #pragma unroll
                    for (int o = 0; o < 4; o++) {
                        float ax = 0.f, ay = 0.f, az = 0.f;
                        #pragma unroll
                        for (int u = 0; u < 7; u++) {
                            const int s = (k + 1 + u) % 7;   // static
                            ax = fmaf(w[u], hxx[s][o], ax);
                            ay = fmaf(w[u], hyy[s][o], ay);
                            az = fmaf(w[u], hxy[s][o], az);
                        }
                        float tr = ax + ay;
                        hp[o] = ax*ay - az*az - 0.05f*tr*tr;
                    }
                    const int orow = row0 + r - 6;
                    *(float4*)(R + (size_t)orow * N_IMG + jc) = h;
                    #pragma unroll
                    for (int o = 0; o < 4; o++) {
                        int b = (int)(f2k(hp[o]) >> 20);
                        if (b == curb) cnt++;
                        else { if (curb >= 0) atomicAdd(&histo[curb], cnt); curb = b; cnt = 1; }
                    }
                }
                #pragma unroll
                for (int t = 0; t < 12; t++) { xm[t] = xc[t]; xc[t] = xp[t]; }
            }
        }
    }
    if (curb >= 0) atomicAdd(&histo[curb], cnt);
    __syncthreads();
    for (int i = tid; i < 4096; i += 256) {
        unsigned c = histo[i];
        if (c) atomicAdd(&g0[i], c);
    }
}

// ---------- level-1 histogram (derives sel0 per block; no select launch) ----------
__global__ __launch_bounds__(256) void hist1_kernel(const float* __restrict__ R,
                                                    const unsigned* __restrict__ g0,
                                                    unsigned* __restrict__ g1)
{
    __shared__ unsigned h[2][4096];
    const int tid = threadIdx.x;
    for (int i = tid; i < 8192; i += 256) ((unsigned*)h)[i] = 0u;

    SelState s = derive0(g0);            // internal barriers also cover h zero-init
    const unsigned p1 = s.p1, p2 = s.p2;
    const bool dual = (p1 != p2);
    const unsigned mask = 0xFFF00000u;
    const int shift = 8;

    const int n4 = NPIX / 4;
    int curb1 = -1; unsigned cnt1 = 0;
    int curb2 = -1; unsigned cnt2 = 0;
    const float4* R4 = (const float4*)R;
    for (int i = blockIdx.x * 256 + tid; i < n4; i += gridDim.x * 256) {
        float4 v = R4[i];
        float vv[4] = {v.x, v.y, v.z, v.w};
        #pragma unroll
        for (int t = 0; t < 4; t++) {
            unsigned k = f2k(vv[t]);
            if ((k & mask) == p1) {
                int b = (int)((k >> shift) & 4095u);
                if (b == curb1) cnt1++;
                else { if (cnt1) atomicAdd(&h[0][curb1], cnt1); curb1 = b; cnt1 = 1; }
            }
            if (dual && (k & mask) == p2) {
                int b = (int)((k >> shift) & 4095u);
                if (b == curb2) cnt2++;
                else { if (cnt2) atomicAdd(&h[1][curb2], cnt2); curb2 = b; cnt2 = 1; }
            }
        }
    }
    if (cnt1) atomicAdd(&h[0][curb1], cnt1);
    if (cnt2) atomicAdd(&h[1][curb2], cnt2);
    __syncthreads();
    for (int i = tid; i < 4096; i += 256) {
        unsigned c0 = h[0][i]; if (c0) atomicAdd(&g1[i], c0);
        if (dual) { unsigned c1 = h[1][i]; if (c1) atomicAdd(&g1[4096 + i], c1); }
    }
}

// ---------- level-2 histogram (derives sel0+sel1 per block) ----------
__global__ __launch_bounds__(256) void hist2_kernel(const float* __restrict__ R,
                                                    const unsigned* __restrict__ g0,
                                                    const unsigned* __restrict__ g1,
                                                    unsigned* __restrict__ g2)
{
    __shared__ unsigned h[2][256];
    const int tid = threadIdx.x;
    for (int i = tid; i < 512; i += 256) ((unsigned*)h)[i] = 0u;

    SelState s = derive0(g0);
    derive1(g1, s);
    const unsigned p1 = s.p1, p2 = s.p2;
    const bool dual = (p1 != p2);
    const unsigned mask = 0xFFFFFF00u;

    const int n4 = NPIX / 4;
    int curb1 = -1; unsigned cnt1 = 0;
    int curb2 = -1; unsigned cnt2 = 0;
    const float4* R4 = (const float4*)R;
    for (int i = blockIdx.x * 256 + tid; i < n4; i += gridDim.x * 256) {
        float4 v = R4[i];
        float vv[4] = {v.x, v.y, v.z, v.w};
        #pragma unroll
        for (int t = 0; t < 4; t++) {
            unsigned k = f2k(vv[t]);
            if ((k & mask) == p1) {
                int b = (int)(k & 255u);
                if (b == curb1) cnt1++;
                else { if (cnt1) atomicAdd(&h[0][curb1], cnt1); curb1 = b; cnt1 = 1; }
            }
            if (dual && (k & mask) == p2) {
                int b = (int)(k & 255u);
                if (b == curb2) cnt2++;
                else { if (cnt2) atomicAdd(&h[1][curb2], cnt2); curb2 = b; cnt2 = 1; }
            }
        }
    }
    if (cnt1) atomicAdd(&h[0][curb1], cnt1);
    if (cnt2) atomicAdd(&h[1][curb2], cnt2);
    __syncthreads();
    if (tid < 256) {
        unsigned c0 = h[0][tid]; if (c0) atomicAdd(&g2[tid], c0);
        if (dual) { unsigned c1 = h[1][tid]; if (c1) atomicAdd(&g2[256 + tid], c1); }
    }
}

__global__ __launch_bounds__(256) void init_kernel(unsigned* __restrict__ g)
{
    const int tid = threadIdx.x;
    for (int i = tid; i < 16384; i += 256) g[i] = 0u;
}

// ---------- NMS: derives full select chain per block -> median; round-0 body ----------
__global__ __launch_bounds__(256) void nms_kernel(const float* __restrict__ R,
                                                  const unsigned* __restrict__ g0,
                                                  const unsigned* __restrict__ g1,
                                                  const unsigned* __restrict__ g2,
                                                  float* __restrict__ out)
{
    const int tid  = threadIdx.x;

    SelState s = derive0(g0);
    derive1(g1, s);
    derive2(g2, s);
    const float med = 0.5f * (k2f(s.p1) + k2f(s.p2));

    const int row0 = blockIdx.y * H_OUT;
    const int jc   = blockIdx.x * NBC + tid * 4;

    float hm[7][4], ct[7][4];

    for (int it = 0; it < 6; ++it) {
        #pragma unroll
        for (int k = 0; k < 7; ++k) {
            const int r = it * 7 + k;
            if (r < HR) {
                const int ri = row0 + r - 3;
                float a[12];
                if ((unsigned)ri < N_IMG) {
                    const float* p = R + (size_t)ri * N_IMG;
                    float4 v1 = *(const float4*)(p + jc);
                    a[4] = (v1.x >= med) ? v1.x : 0.f;
                    a[5] = (v1.y >= med) ? v1.y : 0.f;
                    a[6] = (v1.z >= med) ? v1.z : 0.f;
                    a[7] = (v1.w >= med) ? v1.w : 0.f;
                    if (jc >= 4) {
                        float4 v0 = *(const float4*)(p + jc - 4);
                        a[0] = (v0.x >= med) ? v0.x : 0.f;
                        a[1] = (v0.y >= med) ? v0.y : 0.f;
                        a[2] = (v0.z >= med) ? v0.z : 0.f;
                        a[3] = (v0.w >= med) ? v0.w : 0.f;
                    } else { a[0]=a[1]=a[2]=a[3] = -INFINITY; }
                    if (jc + 4 < N_IMG) {
                        float4 v2 = *(const float4*)(p + jc + 4);
                        a[8]  = (v2.x >= med) ? v2.x : 0.f;
                        a[9]  = (v2.y >= med) ? v2.y : 0.f;
                        a[10] = (v2.z >= med) ? v2.z : 0.f;
                        a[11] = (v2.w >= med) ? v2.w : 0.f;
                    } else { a[8]=a[9]=a[10]=a[11] = -INFINITY; }
                } else {
                    #pragma unroll
                    for (int t = 0; t < 12; t++) a[t] = -INFINITY;
                }
                #pragma unroll
                for (int o = 0; o < 4; o++) {
                    float m = a[o+1];
                    #pragma unroll
                    for (int t = 2; t <= 7; t++) m = fmaxf(m, a[o+t]);
                    hm[k][o] = m;
                    ct[k][o] = a[4+o];
                }
                if (r >= 6) {
                    float4 ov;
                    float* op = &ov.x;
                    #pragma unroll
                    for (int o = 0; o < 4; o++) {
                        float m = hm[(k+1) % 7][o];
                        #pragma unroll
                        for (int u = 1; u < 7; u++) m = fmaxf(m, hm[(k+1+u) % 7][o]);
                        float c = ct[(k+4) % 7][o];
                        op[o] = (c != m) ? 0.f : m;
                    }
                    const int orow = row0 + r - 6;
                    *(float4*)(out + (size_t)orow * N_IMG + jc) = ov;
                }
            }
        }
    }
}

extern "C" void kernel_launch(void* const* d_in, const int* in_sizes, int n_in,
                              void* d_out, int out_size, void* d_ws, size_t ws_size,
                              hipStream_t stream)
{
    const float* x = (const float*)d_in[0];
    float* R = (float*)d_ws;                                   // 64 MB
    unsigned* g0 = (unsigned*)((char*)d_ws + (size_t)N_IMG * N_IMG * 4);
    unsigned* g1 = g0 + 4096;     // level-1 dual: 2 x 4096
    unsigned* g2 = g1 + 8192;     // level-2 dual: 2 x 256
    float* out = (float*)d_out;

    W7 wp;
    {
        double g[7], sm = 0.0;
        for (int i = 0; i < 7; i++) { double ax = (double)i - 3.0; g[i] = exp(-(ax*ax)/50.0); sm += g[i]; }
        for (int i = 0; i < 7; i++) wp.w[i] = (float)(g[i] / sm);
    }

    dim3 sgrid(N_IMG / NBC, N_IMG / H_OUT);   // (4, 128)

    init_kernel<<<1, 256, 0, stream>>>(g0);
    harris_kernel<<<sgrid, 256, 0, stream>>>(x, R, g0, wp);        // + level-0 hist
    hist1_kernel<<<2048, 256, 0, stream>>>(R, g0, g1);             // derives sel0
    hist2_kernel<<<2048, 256, 0, stream>>>(R, g0, g1, g2);         // derives sel0+sel1
    nms_kernel<<<sgrid, 256, 0, stream>>>(R, g0, g1, g2, out);     // derives sel0..2 -> median
}

// Round 4
// 295.209 us; speedup vs baseline: 2.3182x; 1.0133x over previous
//
#include <hip/hip_runtime.h>
#include <math.h>

#define N_IMG 4096
#define NBC   1024        // cols per block (256 threads x 4 cols)
#define H_OUT 32          // output rows per block
#define HR    38          // processed rows per block (H_OUT + 6 halo)
#define NPIX  (N_IMG * N_IMG)

struct W7 { float w[7]; };

__device__ __forceinline__ unsigned f2k(float f) {
    unsigned u = __float_as_uint(f);
    return (u & 0x80000000u) ? ~u : (u | 0x80000000u);
}
__device__ __forceinline__ float k2f(unsigned k) {
    unsigned u = (k & 0x80000000u) ? (k & 0x7fffffffu) : ~k;
    return __uint_as_float(u);
}

// ---------- per-block radix-select re-derivation (no fences, no gates) ----------
// Every block of a consumer kernel recomputes the select result from the
// PREVIOUS kernel's completed histogram (visible at kernel boundary).
struct SelState { unsigned p1, p2, r1, r2; };

template<int BINS>
__device__ void locate_pair(const unsigned* __restrict__ h0,
                            const unsigned* __restrict__ h1,
                            int shift, SelState& s)
{
    __shared__ unsigned scan[256];
    __shared__ unsigned resb[2], resr[2];
    const int tid = threadIdx.x;
    const int per = BINS / 256;
    const bool same = (h0 == h1);

    for (int q = 0; q < 2; q++) {
        if (q == 1 && same) break;
        const unsigned* __restrict__ h = q ? h1 : h0;
        const int base = tid * per;
        unsigned sum = 0;
        #pragma unroll
        for (int i = 0; i < per; i++) sum += h[base + i];
        __syncthreads();                  // protect scan[] reuse across calls
        scan[tid] = sum;
        __syncthreads();
        unsigned v = sum;
        #pragma unroll
        for (int off = 1; off < 256; off <<= 1) {
            unsigned t = (tid >= off) ? scan[tid - off] : 0u;
            __syncthreads();
            v += t;
            scan[tid] = v;
            __syncthreads();
        }
        const unsigned excl = v - sum;
        #pragma unroll
        for (int w = 0; w < 2; w++) {
            const unsigned rank = w ? s.r2 : s.r1;
            const bool mine = w ? (same || q == 1) : (q == 0);
            if (mine && rank >= excl && rank < v) {
                unsigned rr = rank - excl;
                for (int i = 0; i < per; i++) {
                    unsigned c = h[base + i];
                    if (rr < c) { resb[w] = (unsigned)(base + i); resr[w] = rr; break; }
                    rr -= c;
                }
            }
        }
        __syncthreads();
    }
    s.p1 |= resb[0] << shift; s.r1 = resr[0];
    s.p2 |= resb[1] << shift; s.r2 = resr[1];
}

__device__ __forceinline__ SelState derive0(const unsigned* __restrict__ g0) {
    SelState s; s.p1 = 0u; s.p2 = 0u;
    s.r1 = (unsigned)(NPIX / 2 - 1); s.r2 = (unsigned)(NPIX / 2);
    locate_pair<4096>(g0, g0, 20, s);
    return s;
}
__device__ __forceinline__ void derive1(const unsigned* __restrict__ g1, SelState& s) {
    const unsigned* h1 = (s.p1 != s.p2) ? (g1 + 4096) : g1;
    locate_pair<4096>(g1, h1, 8, s);
}
__device__ __forceinline__ void derive2(const unsigned* __restrict__ g2, SelState& s) {
    const unsigned* h1 = (s.p1 != s.p2) ? (g2 + 256) : g2;
    locate_pair<256>(g2, h1, 0, s);
}

// ---------- harris: sobel + products + separable 7x7 gaussian + R + level-0 hist ----------
// Round-0 body. __launch_bounds__(256,2): grid is 512 blocks = 2 blocks/CU = 2
// waves/EU ALWAYS, so capping at 2 waves/EU loses nothing and raises the VGPR
// budget to 256 -> the 84-float ring + 36-float rolling rows stay in registers
// (VGPR=88 before meant ~60+ floats/thread spilled to scratch).
__global__ __launch_bounds__(256, 2) void harris_kernel(const float* __restrict__ x,
                                                        float* __restrict__ R,
                                                        unsigned* __restrict__ g0,
                                                        W7 wp)
{
    __shared__ unsigned histo[4096];
    const int tid = threadIdx.x;
    for (int i = tid; i < 4096; i += 256) histo[i] = 0;
    __syncthreads();

    const int row0 = blockIdx.y * H_OUT;
    const int jc   = blockIdx.x * NBC + tid * 4;   // first owned column
    const float* w = wp.w;

    float xm[12], xc[12], xp[12];                  // rolling x rows (cols jc-4..jc+7)
    float hxx[7][4], hyy[7][4], hxy[7][4];         // 7-deep ring of h rows

    auto loadrow = [&](int ri, float* d) {
        if ((unsigned)ri < N_IMG) {
            const float* p = x + (size_t)ri * N_IMG;
            float4 v0 = make_float4(0.f,0.f,0.f,0.f), v2 = make_float4(0.f,0.f,0.f,0.f);
            if (jc >= 4) v0 = *(const float4*)(p + jc - 4);
            float4 v1 = *(const float4*)(p + jc);
            if (jc + 4 < N_IMG) v2 = *(const float4*)(p + jc + 4);
            d[0]=v0.x; d[1]=v0.y; d[2]=v0.z; d[3]=v0.w;
            d[4]=v1.x; d[5]=v1.y; d[6]=v1.z; d[7]=v1.w;
            d[8]=v2.x; d[9]=v2.y; d[10]=v2.z; d[11]=v2.w;
        } else {
            #pragma unroll
            for (int t = 0; t < 12; t++) d[t] = 0.f;
        }
    };

    loadrow(row0 - 4, xm);
    loadrow(row0 - 3, xc);

    int curb = -1; unsigned cnt = 0;   // histogram run-length state

    for (int it = 0; it < 6; ++it) {
        #pragma unroll
        for (int k = 0; k < 7; ++k) {
            const int r = it * 7 + k;          // ring slot == k (r mod 7)
            if (r < HR) {
                const int ri = row0 + r - 3;   // image row of this h row
                loadrow(ri + 1, xp);

                float sxx[4] = {0,0,0,0}, syy[4] = {0,0,0,0}, sxy[4] = {0,0,0,0};
                if ((unsigned)ri < N_IMG) {
                    float dc[12], rd[12];
                    #pragma unroll
                    for (int t = 0; t < 12; t++) {
                        dc[t] = xm[t] + 2.f * xc[t] + xp[t];
                        rd[t] = xp[t] - xm[t];
                    }
                    #pragma unroll
                    for (int t = 0; t < 10; t++) {
                        float ix = dc[t+2] - dc[t];
                        float iy = rd[t] + 2.f * rd[t+1] + rd[t+2];
                        if ((unsigned)(jc - 3 + t) >= N_IMG) { ix = 0.f; iy = 0.f; }
                        float xx = ix*ix, yy = iy*iy, xy = ix*iy;
                        #pragma unroll
                        for (int o = 0; o < 4; o++) {
                            int v = t - o;
                            if (v >= 0 && v < 7) {
                                sxx[o] = fmaf(w[v], xx, sxx[o]);
                                syy[o] = fmaf(w[v], yy, syy[o]);
                                sxy[o] = fmaf(w[v], xy, sxy[o]);
                            }
                        }
                    }
                }
                #pragma unroll
                for (int o = 0; o < 4; o++) {
                    hxx[k][o] = sxx[o]; hyy[k][o] = syy[o]; hxy[k][o] = sxy[o];
                }

                if (r >= 6) {
                    float4 h;
                    float* hp = &h.x;
                    #pragma unroll
                    for (int o = 0; o < 4; o++) {
                        float ax = 0.f, ay = 0.f, az = 0.f;
                        #pragma unroll
                        for (int u = 0; u < 7; u++) {
                            const int s = (k + 1 + u) % 7;   // static
                            ax = fmaf(w[u], hxx[s][o], ax);
                            ay = fmaf(w[u], hyy[s][o], ay);
                            az = fmaf(w[u], hxy[s][o], az);
                        }
                        float tr = ax + ay;
                        hp[o] = ax*ay - az*az - 0.05f*tr*tr;
                    }
                    const int orow = row0 + r - 6;
                    *(float4*)(R + (size_t)orow * N_IMG + jc) = h;
                    #pragma unroll
                    for (int o = 0; o < 4; o++) {
                        int b = (int)(f2k(hp[o]) >> 20);
                        if (b == curb) cnt++;
                        else { if (curb >= 0) atomicAdd(&histo[curb], cnt); curb = b; cnt = 1; }
                    }
                }
                #pragma unroll
                for (int t = 0; t < 12; t++) { xm[t] = xc[t]; xc[t] = xp[t]; }
            }
        }
    }
    if (curb >= 0) atomicAdd(&histo[curb], cnt);
    __syncthreads();
    for (int i = tid; i < 4096; i += 256) {
        unsigned c = histo[i];
        if (c) atomicAdd(&g0[i], c);
    }
}

// ---------- level-1 histogram (derives sel0 per block; no select launch) ----------
__global__ __launch_bounds__(256) void hist1_kernel(const float* __restrict__ R,
                                                    const unsigned* __restrict__ g0,
                                                    unsigned* __restrict__ g1)
{
    __shared__ unsigned h[2][4096];
    const int tid = threadIdx.x;
    for (int i = tid; i < 8192; i += 256) ((unsigned*)h)[i] = 0u;

    SelState s = derive0(g0);            // internal barriers also cover h zero-init
    const unsigned p1 = s.p1, p2 = s.p2;
    const bool dual = (p1 != p2);
    const unsigned mask = 0xFFF00000u;
    const int shift = 8;

    const int n4 = NPIX / 4;
    int curb1 = -1; unsigned cnt1 = 0;
    int curb2 = -1; unsigned cnt2 = 0;
    const float4* R4 = (const float4*)R;
    for (int i = blockIdx.x * 256 + tid; i < n4; i += gridDim.x * 256) {
        float4 v = R4[i];
        float vv[4] = {v.x, v.y, v.z, v.w};
        #pragma unroll
        for (int t = 0; t < 4; t++) {
            unsigned k = f2k(vv[t]);
            if ((k & mask) == p1) {
                int b = (int)((k >> shift) & 4095u);
                if (b == curb1) cnt1++;
                else { if (cnt1) atomicAdd(&h[0][curb1], cnt1); curb1 = b; cnt1 = 1; }
            }
            if (dual && (k & mask) == p2) {
                int b = (int)((k >> shift) & 4095u);
                if (b == curb2) cnt2++;
                else { if (cnt2) atomicAdd(&h[1][curb2], cnt2); curb2 = b; cnt2 = 1; }
            }
        }
    }
    if (cnt1) atomicAdd(&h[0][curb1], cnt1);
    if (cnt2) atomicAdd(&h[1][curb2], cnt2);
    __syncthreads();
    for (int i = tid; i < 4096; i += 256) {
        unsigned c0 = h[0][i]; if (c0) atomicAdd(&g1[i], c0);
        if (dual) { unsigned c1 = h[1][i]; if (c1) atomicAdd(&g1[4096 + i], c1); }
    }
}

// ---------- level-2 histogram (derives sel0+sel1 per block) ----------
__global__ __launch_bounds__(256) void hist2_kernel(const float* __restrict__ R,
                                                    const unsigned* __restrict__ g0,
                                                    const unsigned* __restrict__ g1,
                                                    unsigned* __restrict__ g2)
{
    __shared__ unsigned h[2][256];
    const int tid = threadIdx.x;
    for (int i = tid; i < 512; i += 256) ((unsigned*)h)[i] = 0u;

    SelState s = derive0(g0);
    derive1(g1, s);
    const unsigned p1 = s.p1, p2 = s.p2;
    const bool dual = (p1 != p2);
    const unsigned mask = 0xFFFFFF00u;

    const int n4 = NPIX / 4;
    int curb1 = -1; unsigned cnt1 = 0;
    int curb2 = -1; unsigned cnt2 = 0;
    const float4* R4 = (const float4*)R;
    for (int i = blockIdx.x * 256 + tid; i < n4; i += gridDim.x * 256) {
        float4 v = R4[i];
        float vv[4] = {v.x, v.y, v.z, v.w};
        #pragma unroll
        for (int t = 0; t < 4; t++) {
            unsigned k = f2k(vv[t]);
            if ((k & mask) == p1) {
                int b = (int)(k & 255u);
                if (b == curb1) cnt1++;
                else { if (cnt1) atomicAdd(&h[0][curb1], cnt1); curb1 = b; cnt1 = 1; }
            }
            if (dual && (k & mask) == p2) {
                int b = (int)(k & 255u);
                if (b == curb2) cnt2++;
                else { if (cnt2) atomicAdd(&h[1][curb2], cnt2); curb2 = b; cnt2 = 1; }
            }
        }
    }
    if (cnt1) atomicAdd(&h[0][curb1], cnt1);
    if (cnt2) atomicAdd(&h[1][curb2], cnt2);
    __syncthreads();
    if (tid < 256) {
        unsigned c0 = h[0][tid]; if (c0) atomicAdd(&g2[tid], c0);
        if (dual) { unsigned c1 = h[1][tid]; if (c1) atomicAdd(&g2[256 + tid], c1); }
    }
}

__global__ __launch_bounds__(256) void init_kernel(unsigned* __restrict__ g)
{
    const int tid = threadIdx.x;
    for (int i = tid; i < 16384; i += 256) g[i] = 0u;
}

// ---------- NMS: derives full select chain per block -> median; round-0 body ----------
// __launch_bounds__(256,2): same reasoning as harris (grid = 512 blocks = 2
// waves/EU resident regardless; free the allocator, keep hm/ct rings in VGPRs).
__global__ __launch_bounds__(256, 2) void nms_kernel(const float* __restrict__ R,
                                                     const unsigned* __restrict__ g0,
                                                     const unsigned* __restrict__ g1,
                                                     const unsigned* __restrict__ g2,
                                                     float* __restrict__ out)
{
    const int tid  = threadIdx.x;

    SelState s = derive0(g0);
    derive1(g1, s);
    derive2(g2, s);
    const float med = 0.5f * (k2f(s.p1) + k2f(s.p2));

    const int row0 = blockIdx.y * H_OUT;
    const int jc   = blockIdx.x * NBC + tid * 4;

    float hm[7][4], ct[7][4];

    for (int it = 0; it < 6; ++it) {
        #pragma unroll
        for (int k = 0; k < 7; ++k) {
            const int r = it * 7 + k;
            if (r < HR) {
                const int ri = row0 + r - 3;
                float a[12];
                if ((unsigned)ri < N_IMG) {
                    const float* p = R + (size_t)ri * N_IMG;
                    float4 v1 = *(const float4*)(p + jc);
                    a[4] = (v1.x >= med) ? v1.x : 0.f;
                    a[5] = (v1.y >= med) ? v1.y : 0.f;
                    a[6] = (v1.z >= med) ? v1.z : 0.f;
                    a[7] = (v1.w >= med) ? v1.w : 0.f;
                    if (jc >= 4) {
                        float4 v0 = *(const float4*)(p + jc - 4);
                        a[0] = (v0.x >= med) ? v0.x : 0.f;
                        a[1] = (v0.y >= med) ? v0.y : 0.f;
                        a[2] = (v0.z >= med) ? v0.z : 0.f;
                        a[3] = (v0.w >= med) ? v0.w : 0.f;
                    } else { a[0]=a[1]=a[2]=a[3] = -INFINITY; }
                    if (jc + 4 < N_IMG) {
                        float4 v2 = *(const float4*)(p + jc + 4);
                        a[8]  = (v2.x >= med) ? v2.x : 0.f;
                        a[9]  = (v2.y >= med) ? v2.y : 0.f;
                        a[10] = (v2.z >= med) ? v2.z : 0.f;
                        a[11] = (v2.w >= med) ? v2.w : 0.f;
                    } else { a[8]=a[9]=a[10]=a[11] = -INFINITY; }
                } else {
                    #pragma unroll
                    for (int t = 0; t < 12; t++) a[t] = -INFINITY;
                }
                #pragma unroll
                for (int o = 0; o < 4; o++) {
                    float m = a[o+1];
                    #pragma unroll
                    for (int t = 2; t <= 7; t++) m = fmaxf(m, a[o+t]);
                    hm[k][o] = m;
                    ct[k][o] = a[4+o];
                }
                if (r >= 6) {
                    float4 ov;
                    float* op = &ov.x;
                    #pragma unroll
                    for (int o = 0; o < 4; o++) {
                        float m = hm[(k+1) % 7][o];
                        #pragma unroll
                        for (int u = 1; u < 7; u++) m = fmaxf(m, hm[(k+1+u) % 7][o]);
                        float c = ct[(k+4) % 7][o];
                        op[o] = (c != m) ? 0.f : m;
                    }
                    const int orow = row0 + r - 6;
                    *(float4*)(out + (size_t)orow * N_IMG + jc) = ov;
                }
            }
        }
    }
}

extern "C" void kernel_launch(void* const* d_in, const int* in_sizes, int n_in,
                              void* d_out, int out_size, void* d_ws, size_t ws_size,
                              hipStream_t stream)
{
    const float* x = (const float*)d_in[0];
    float* R = (float*)d_ws;                                   // 64 MB
    unsigned* g0 = (unsigned*)((char*)d_ws + (size_t)N_IMG * N_IMG * 4);
    unsigned* g1 = g0 + 4096;     // level-1 dual: 2 x 4096
    unsigned* g2 = g1 + 8192;     // level-2 dual: 2 x 256
    float* out = (float*)d_out;

    W7 wp;
    {
        double g[7], sm = 0.0;
        for (int i = 0; i < 7; i++) { double ax = (double)i - 3.0; g[i] = exp(-(ax*ax)/50.0); sm += g[i]; }
        for (int i = 0; i < 7; i++) wp.w[i] = (float)(g[i] / sm);
    }

    dim3 sgrid(N_IMG / NBC, N_IMG / H_OUT);   // (4, 128)

    init_kernel<<<1, 256, 0, stream>>>(g0);
    harris_kernel<<<sgrid, 256, 0, stream>>>(x, R, g0, wp);        // + level-0 hist
    hist1_kernel<<<2048, 256, 0, stream>>>(R, g0, g1);             // derives sel0
    hist2_kernel<<<2048, 256, 0, stream>>>(R, g0, g1, g2);         // derives sel0+sel1
    nms_kernel<<<sgrid, 256, 0, stream>>>(R, g0, g1, g2, out);     // derives sel0..2 -> median
}

// Round 5
// 289.147 us; speedup vs baseline: 2.3668x; 1.0210x over previous
//
#include <hip/hip_runtime.h>
#include <math.h>

#define N_IMG 4096
#define NBC   1024        // cols per block (256 threads x 4 cols)
#define H_OUT 32          // output rows per block
#define HR    38          // processed rows per block (H_OUT + 6 halo)
#define NPIX  (N_IMG * N_IMG)

struct W7 { float w[7]; };

__device__ __forceinline__ unsigned f2k(float f) {
    unsigned u = __float_as_uint(f);
    return (u & 0x80000000u) ? ~u : (u | 0x80000000u);
}
__device__ __forceinline__ float k2f(unsigned k) {
    unsigned u = (k & 0x80000000u) ? (k & 0x7fffffffu) : ~k;
    return __uint_as_float(u);
}

// ---------- per-block radix-select re-derivation (no fences, no gates) ----------
struct SelState { unsigned p1, p2, r1, r2; };

template<int BINS>
__device__ void locate_pair(const unsigned* __restrict__ h0,
                            const unsigned* __restrict__ h1,
                            int shift, SelState& s)
{
    __shared__ unsigned scan[256];
    __shared__ unsigned resb[2], resr[2];
    const int tid = threadIdx.x;
    const int per = BINS / 256;
    const bool same = (h0 == h1);

    for (int q = 0; q < 2; q++) {
        if (q == 1 && same) break;
        const unsigned* __restrict__ h = q ? h1 : h0;
        const int base = tid * per;
        unsigned sum = 0;
        #pragma unroll
        for (int i = 0; i < per; i++) sum += h[base + i];
        __syncthreads();                  // protect scan[] reuse across calls
        scan[tid] = sum;
        __syncthreads();
        unsigned v = sum;
        #pragma unroll
        for (int off = 1; off < 256; off <<= 1) {
            unsigned t = (tid >= off) ? scan[tid - off] : 0u;
            __syncthreads();
            v += t;
            scan[tid] = v;
            __syncthreads();
        }
        const unsigned excl = v - sum;
        #pragma unroll
        for (int w = 0; w < 2; w++) {
            const unsigned rank = w ? s.r2 : s.r1;
            const bool mine = w ? (same || q == 1) : (q == 0);
            if (mine && rank >= excl && rank < v) {
                unsigned rr = rank - excl;
                for (int i = 0; i < per; i++) {
                    unsigned c = h[base + i];
                    if (rr < c) { resb[w] = (unsigned)(base + i); resr[w] = rr; break; }
                    rr -= c;
                }
            }
        }
        __syncthreads();
    }
    s.p1 |= resb[0] << shift; s.r1 = resr[0];
    s.p2 |= resb[1] << shift; s.r2 = resr[1];
}

__device__ __forceinline__ SelState derive0(const unsigned* __restrict__ g0) {
    SelState s; s.p1 = 0u; s.p2 = 0u;
    s.r1 = (unsigned)(NPIX / 2 - 1); s.r2 = (unsigned)(NPIX / 2);
    locate_pair<4096>(g0, g0, 20, s);
    return s;
}
__device__ __forceinline__ void derive1(const unsigned* __restrict__ g1, SelState& s) {
    const unsigned* h1 = (s.p1 != s.p2) ? (g1 + 4096) : g1;
    locate_pair<4096>(g1, h1, 8, s);
}
__device__ __forceinline__ void derive2(const unsigned* __restrict__ g2, SelState& s) {
    const unsigned* h1 = (s.p1 != s.p2) ? (g2 + 256) : g2;
    locate_pair<256>(g2, h1, 0, s);
}

// ---------- harris: sobel + products + separable 7x7 gaussian + R + level-0 hist ----------
// v5: SCATTER-ACCUMULATE vertical gaussian. Instead of a 7-deep ring of h rows
// (12 accvgpr-writes/row + 84 accvgpr-reads/output + 7-deep dependent sum chains),
// keep 7 live accumulators per col/channel: when h-row r is produced, scatter
// acc[(r+d)%7] += w[6-d]*h (84 INDEPENDENT fmas). Output = 1 read + reset.
// A static 7-step prologue (d >= 6-r) prevents slot pollution.
__global__ __launch_bounds__(256, 2) void harris_kernel(const float* __restrict__ x,
                                                        float* __restrict__ R,
                                                        unsigned* __restrict__ g0,
                                                        W7 wp)
{
    __shared__ unsigned histo[4096];
    const int tid = threadIdx.x;
    for (int i = tid; i < 4096; i += 256) histo[i] = 0;
    __syncthreads();

    const int row0 = blockIdx.y * H_OUT;
    const int jc   = blockIdx.x * NBC + tid * 4;   // first owned column
    const float* w = wp.w;
    const bool edge = (jc < 4) || (jc >= N_IMG - 8);   // lanes needing col clamps

    float xm[12], xc[12], xp[12];                  // rolling x rows (cols jc-4..jc+7)
    float axx[7][4], ayy[7][4], axy[7][4];         // 7 pending vertical accumulators

    #pragma unroll
    for (int m = 0; m < 7; m++)
        #pragma unroll
        for (int o = 0; o < 4; o++) { axx[m][o] = 0.f; ayy[m][o] = 0.f; axy[m][o] = 0.f; }

    auto loadrow = [&](int ri, float* d) {
        if ((unsigned)ri < N_IMG) {
            const float* p = x + (size_t)ri * N_IMG;
            float4 v0 = make_float4(0.f,0.f,0.f,0.f), v2 = make_float4(0.f,0.f,0.f,0.f);
            if (jc >= 4) v0 = *(const float4*)(p + jc - 4);
            float4 v1 = *(const float4*)(p + jc);
            if (jc + 4 < N_IMG) v2 = *(const float4*)(p + jc + 4);
            d[0]=v0.x; d[1]=v0.y; d[2]=v0.z; d[3]=v0.w;
            d[4]=v1.x; d[5]=v1.y; d[6]=v1.z; d[7]=v1.w;
            d[8]=v2.x; d[9]=v2.y; d[10]=v2.z; d[11]=v2.w;
        } else {
            #pragma unroll
            for (int t = 0; t < 12; t++) d[t] = 0.f;
        }
    };

    loadrow(row0 - 4, xm);
    loadrow(row0 - 3, xc);

    int curb = -1; unsigned cnt = 0;   // histogram run-length state

    // step: process h-row r (ring slot k == r%7). dmin restricts scatter targets
    // during the prologue so never-emitted outputs q<6 don't pollute slots.
    auto step = [&](int r, int k, int dmin, bool emit) {
        const int ri = row0 + r - 3;   // image row of this h row
        loadrow(ri + 1, xp);

        if ((unsigned)ri < N_IMG) {
            float dc[12], rd[12];
            #pragma unroll
            for (int t = 0; t < 12; t++) {
                dc[t] = xm[t] + 2.f * xc[t] + xp[t];
                rd[t] = xp[t] - xm[t];
            }
            float ixv[10], iyv[10];
            #pragma unroll
            for (int t = 0; t < 10; t++) {
                ixv[t] = dc[t+2] - dc[t];
                iyv[t] = rd[t] + 2.f * rd[t+1] + rd[t+2];
            }
            if (edge) {                 // execz-skipped by interior waves
                #pragma unroll
                for (int t = 0; t < 10; t++)
                    if ((unsigned)(jc - 3 + t) >= N_IMG) { ixv[t] = 0.f; iyv[t] = 0.f; }
            }
            float sxx[4] = {0,0,0,0}, syy[4] = {0,0,0,0}, sxy[4] = {0,0,0,0};
            #pragma unroll
            for (int t = 0; t < 10; t++) {
                float ix = ixv[t], iy = iyv[t];
                float xx = ix*ix, yy = iy*iy, xy = ix*iy;
                #pragma unroll
                for (int o = 0; o < 4; o++) {
                    const int v = t - o;
                    if (v >= 0 && v < 7) {
                        sxx[o] = fmaf(w[v], xx, sxx[o]);
                        syy[o] = fmaf(w[v], yy, syy[o]);
                        sxy[o] = fmaf(w[v], xy, sxy[o]);
                    }
                }
            }
            // scatter into the 7 pending outputs: h-row r has weight w[6-d]
            // in output q = r+d (slot (k+d)%7). All fmas independent.
            #pragma unroll
            for (int d = 0; d < 7; d++) {
                if (d >= dmin) {
                    const int m = (k + d) % 7;   // static after unroll
                    #pragma unroll
                    for (int o = 0; o < 4; o++) {
                        axx[m][o] = fmaf(w[6-d], sxx[o], axx[m][o]);
                        ayy[m][o] = fmaf(w[6-d], syy[o], ayy[m][o]);
                        axy[m][o] = fmaf(w[6-d], sxy[o], axy[m][o]);
                    }
                }
            }
        }

        if (emit) {                     // output q == r completes in slot k
            float4 h;
            float* hp = &h.x;
            #pragma unroll
            for (int o = 0; o < 4; o++) {
                float ax = axx[k][o], ay = ayy[k][o], az = axy[k][o];
                axx[k][o] = 0.f; ayy[k][o] = 0.f; axy[k][o] = 0.f;
                float tr = ax + ay;
                hp[o] = ax*ay - az*az - 0.05f*tr*tr;
            }
            const int orow = row0 + r - 6;
            *(float4*)(R + (size_t)orow * N_IMG + jc) = h;
            #pragma unroll
            for (int o = 0; o < 4; o++) {
                int b = (int)(f2k(hp[o]) >> 20);
                if (b == curb) cnt++;
                else { if (curb >= 0) atomicAdd(&histo[curb], cnt); curb = b; cnt = 1; }
            }
        }
        #pragma unroll
        for (int t = 0; t < 12; t++) { xm[t] = xc[t]; xc[t] = xp[t]; }
    };

    // prologue rows 0..6: restricted scatter (only targets q >= 6); r=6 emits q=6
    #pragma unroll
    for (int rr = 0; rr < 7; ++rr)
        step(rr, rr, 6 - rr, rr == 6);
    // main rows 7..37: full scatter, every row emits
    for (int it = 1; it < 6; ++it) {
        #pragma unroll
        for (int k = 0; k < 7; ++k) {
            const int r = it * 7 + k;
            if (r < HR) step(r, k, 0, true);
        }
    }

    if (curb >= 0) atomicAdd(&histo[curb], cnt);
    __syncthreads();
    for (int i = tid; i < 4096; i += 256) {
        unsigned c = histo[i];
        if (c) atomicAdd(&g0[i], c);
    }
}

// ---------- level-1 histogram (derives sel0 per block; no select launch) ----------
__global__ __launch_bounds__(256) void hist1_kernel(const float* __restrict__ R,
                                                    const unsigned* __restrict__ g0,
                                                    unsigned* __restrict__ g1)
{
    __shared__ unsigned h[2][4096];
    const int tid = threadIdx.x;
    for (int i = tid; i < 8192; i += 256) ((unsigned*)h)[i] = 0u;

    SelState s = derive0(g0);            // internal barriers also cover h zero-init
    const unsigned p1 = s.p1, p2 = s.p2;
    const bool dual = (p1 != p2);
    const unsigned mask = 0xFFF00000u;
    const int shift = 8;

    const int n4 = NPIX / 4;
    int curb1 = -1; unsigned cnt1 = 0;
    int curb2 = -1; unsigned cnt2 = 0;
    const float4* R4 = (const float4*)R;
    for (int i = blockIdx.x * 256 + tid; i < n4; i += gridDim.x * 256) {
        float4 v = R4[i];
        float vv[4] = {v.x, v.y, v.z, v.w};
        #pragma unroll
        for (int t = 0; t < 4; t++) {
            unsigned k = f2k(vv[t]);
            if ((k & mask) == p1) {
                int b = (int)((k >> shift) & 4095u);
                if (b == curb1) cnt1++;
                else { if (cnt1) atomicAdd(&h[0][curb1], cnt1); curb1 = b; cnt1 = 1; }
            }
            if (dual && (k & mask) == p2) {
                int b = (int)((k >> shift) & 4095u);
                if (b == curb2) cnt2++;
                else { if (cnt2) atomicAdd(&h[1][curb2], cnt2); curb2 = b; cnt2 = 1; }
            }
        }
    }
    if (cnt1) atomicAdd(&h[0][curb1], cnt1);
    if (cnt2) atomicAdd(&h[1][curb2], cnt2);
    __syncthreads();
    for (int i = tid; i < 4096; i += 256) {
        unsigned c0 = h[0][i]; if (c0) atomicAdd(&g1[i], c0);
        if (dual) { unsigned c1 = h[1][i]; if (c1) atomicAdd(&g1[4096 + i], c1); }
    }
}

// ---------- level-2 histogram (derives sel0+sel1 per block) ----------
__global__ __launch_bounds__(256) void hist2_kernel(const float* __restrict__ R,
                                                    const unsigned* __restrict__ g0,
                                                    const unsigned* __restrict__ g1,
                                                    unsigned* __restrict__ g2)
{
    __shared__ unsigned h[2][256];
    const int tid = threadIdx.x;
    for (int i = tid; i < 512; i += 256) ((unsigned*)h)[i] = 0u;

    SelState s = derive0(g0);
    derive1(g1, s);
    const unsigned p1 = s.p1, p2 = s.p2;
    const bool dual = (p1 != p2);
    const unsigned mask = 0xFFFFFF00u;

    const int n4 = NPIX / 4;
    int curb1 = -1; unsigned cnt1 = 0;
    int curb2 = -1; unsigned cnt2 = 0;
    const float4* R4 = (const float4*)R;
    for (int i = blockIdx.x * 256 + tid; i < n4; i += gridDim.x * 256) {
        float4 v = R4[i];
        float vv[4] = {v.x, v.y, v.z, v.w};
        #pragma unroll
        for (int t = 0; t < 4; t++) {
            unsigned k = f2k(vv[t]);
            if ((k & mask) == p1) {
                int b = (int)(k & 255u);
                if (b == curb1) cnt1++;
                else { if (cnt1) atomicAdd(&h[0][curb1], cnt1); curb1 = b; cnt1 = 1; }
            }
            if (dual && (k & mask) == p2) {
                int b = (int)(k & 255u);
                if (b == curb2) cnt2++;
                else { if (cnt2) atomicAdd(&h[1][curb2], cnt2); curb2 = b; cnt2 = 1; }
            }
        }
    }
    if (cnt1) atomicAdd(&h[0][curb1], cnt1);
    if (cnt2) atomicAdd(&h[1][curb2], cnt2);
    __syncthreads();
    if (tid < 256) {
        unsigned c0 = h[0][tid]; if (c0) atomicAdd(&g2[tid], c0);
        if (dual) { unsigned c1 = h[1][tid]; if (c1) atomicAdd(&g2[256 + tid], c1); }
    }
}

__global__ __launch_bounds__(256) void init_kernel(unsigned* __restrict__ g)
{
    const int tid = threadIdx.x;
    for (int i = tid; i < 16384; i += 256) g[i] = 0u;
}

// ---------- NMS: scatter-MAX vertical pass (same restructure as harris) ----------
__global__ __launch_bounds__(256, 2) void nms_kernel(const float* __restrict__ R,
                                                     const unsigned* __restrict__ g0,
                                                     const unsigned* __restrict__ g1,
                                                     const unsigned* __restrict__ g2,
                                                     float* __restrict__ out)
{
    const int tid  = threadIdx.x;

    SelState s = derive0(g0);
    derive1(g1, s);
    derive2(g2, s);
    const float med = 0.5f * (k2f(s.p1) + k2f(s.p2));

    const int row0 = blockIdx.y * H_OUT;
    const int jc   = blockIdx.x * NBC + tid * 4;

    float vm[7][4];                    // 7 pending vertical-max accumulators
    float ct[7][4];                    // center-value ring
    #pragma unroll
    for (int m = 0; m < 7; m++)
        #pragma unroll
        for (int o = 0; o < 4; o++) vm[m][o] = -INFINITY;

    auto loadrowT = [&](int ri, float* d) {
        if ((unsigned)ri < N_IMG) {
            const float* p = R + (size_t)ri * N_IMG;
            float4 v1 = *(const float4*)(p + jc);
            d[4] = (v1.x >= med) ? v1.x : 0.f;
            d[5] = (v1.y >= med) ? v1.y : 0.f;
            d[6] = (v1.z >= med) ? v1.z : 0.f;
            d[7] = (v1.w >= med) ? v1.w : 0.f;
            if (jc >= 4) {
                float4 v0 = *(const float4*)(p + jc - 4);
                d[0] = (v0.x >= med) ? v0.x : 0.f;
                d[1] = (v0.y >= med) ? v0.y : 0.f;
                d[2] = (v0.z >= med) ? v0.z : 0.f;
                d[3] = (v0.w >= med) ? v0.w : 0.f;
            } else { d[0]=d[1]=d[2]=d[3] = -INFINITY; }
            if (jc + 4 < N_IMG) {
                float4 v2 = *(const float4*)(p + jc + 4);
                d[8]  = (v2.x >= med) ? v2.x : 0.f;
                d[9]  = (v2.y >= med) ? v2.y : 0.f;
                d[10] = (v2.z >= med) ? v2.z : 0.f;
                d[11] = (v2.w >= med) ? v2.w : 0.f;
            } else { d[8]=d[9]=d[10]=d[11] = -INFINITY; }
        } else {
            #pragma unroll
            for (int t = 0; t < 12; t++) d[t] = -INFINITY;
        }
    };

    auto stepn = [&](int r, int k, int dmin, bool emit) {
        const int ri = row0 + r - 3;
        float a[12];
        loadrowT(ri, a);
        float hm[4];
        #pragma unroll
        for (int o = 0; o < 4; o++) {
            // 7-wide horizontal max, tree form
            float m01 = fmaxf(a[o+1], a[o+2]);
            float m23 = fmaxf(a[o+3], a[o+4]);
            float m45 = fmaxf(a[o+5], a[o+6]);
            hm[o] = fmaxf(fmaxf(m01, m23), fmaxf(m45, a[o+7]));
            ct[k][o] = a[4+o];
        }
        #pragma unroll
        for (int d = 0; d < 7; d++) {
            if (d >= dmin) {
                const int m = (k + d) % 7;   // static after unroll
                #pragma unroll
                for (int o = 0; o < 4; o++)
                    vm[m][o] = fmaxf(vm[m][o], hm[o]);
            }
        }
        if (emit) {
            float4 ov;
            float* op = &ov.x;
            #pragma unroll
            for (int o = 0; o < 4; o++) {
                float m = vm[k][o];
                vm[k][o] = -INFINITY;
                float c = ct[(k+4) % 7][o];
                op[o] = (c != m) ? 0.f : m;
            }
            const int orow = row0 + r - 6;
            *(float4*)(out + (size_t)orow * N_IMG + jc) = ov;
        }
    };

    #pragma unroll
    for (int rr = 0; rr < 7; ++rr)
        stepn(rr, rr, 6 - rr, rr == 6);
    for (int it = 1; it < 6; ++it) {
        #pragma unroll
        for (int k = 0; k < 7; ++k) {
            const int r = it * 7 + k;
            if (r < HR) stepn(r, k, 0, true);
        }
    }
}

extern "C" void kernel_launch(void* const* d_in, const int* in_sizes, int n_in,
                              void* d_out, int out_size, void* d_ws, size_t ws_size,
                              hipStream_t stream)
{
    const float* x = (const float*)d_in[0];
    float* R = (float*)d_ws;                                   // 64 MB
    unsigned* g0 = (unsigned*)((char*)d_ws + (size_t)N_IMG * N_IMG * 4);
    unsigned* g1 = g0 + 4096;     // level-1 dual: 2 x 4096
    unsigned* g2 = g1 + 8192;     // level-2 dual: 2 x 256
    float* out = (float*)d_out;

    W7 wp;
    {
        double g[7], sm = 0.0;
        for (int i = 0; i < 7; i++) { double ax = (double)i - 3.0; g[i] = exp(-(ax*ax)/50.0); sm += g[i]; }
        for (int i = 0; i < 7; i++) wp.w[i] = (float)(g[i] / sm);
    }

    dim3 sgrid(N_IMG / NBC, N_IMG / H_OUT);   // (4, 128)

    init_kernel<<<1, 256, 0, stream>>>(g0);
    harris_kernel<<<sgrid, 256, 0, stream>>>(x, R, g0, wp);        // + level-0 hist
    hist1_kernel<<<2048, 256, 0, stream>>>(R, g0, g1);             // derives sel0
    hist2_kernel<<<2048, 256, 0, stream>>>(R, g0, g1, g2);         // derives sel0+sel1
    nms_kernel<<<sgrid, 256, 0, stream>>>(R, g0, g1, g2, out);     // derives sel0..2 -> median
}